// Round 1
// baseline (300.150 us; speedup 1.0000x reference)
//
#include <hip/hip_runtime.h>
#include <math.h>

#define B 4
#define N 4096
#define M 8192
#define C 64
#define NB 512
#define XMIN (-64.0f)
#define INV_BW 4.0f   // bucket width 0.25

__device__ __forceinline__ int bucket_of(float v) {
    int k = (int)floorf((v - XMIN) * INV_BW);
    return min(max(k, 0), NB - 1);
}

// One block per batch, 512 threads. Counting sort of xz into 512 buckets.
__global__ __launch_bounds__(512) void bin_kernel(
    const float* __restrict__ xz,
    int* __restrict__ bucket_start,   // [B][NB+1]
    int* __restrict__ perm,           // [B][M]
    float* __restrict__ xz_s)         // [B][M] sorted-by-bucket coords
{
    __shared__ int scan[NB];
    __shared__ int run[NB];
    const int b = blockIdx.x;
    const int t = threadIdx.x;
    constexpr int PPT = M / 512;  // 16 points per thread
    float val[PPT];
    int key[PPT];

    scan[t] = 0;
    __syncthreads();

    for (int j = 0; j < PPT; ++j) {
        int i = j * 512 + t;              // coalesced
        float v = xz[b * M + i];
        val[j] = v;
        int k = bucket_of(v);
        key[j] = k;
        atomicAdd(&scan[k], 1);
    }
    __syncthreads();

    int cnt = scan[t];
    // Hillis-Steele inclusive scan over NB == blockDim
    for (int off = 1; off < NB; off <<= 1) {
        int add = (t >= off) ? scan[t - off] : 0;
        __syncthreads();
        scan[t] += add;
        __syncthreads();
    }

    int start = scan[t] - cnt;
    run[t] = start;
    bucket_start[b * (NB + 1) + t] = start;
    if (t == NB - 1) bucket_start[b * (NB + 1) + NB] = scan[t];  // == M
    __syncthreads();

    for (int j = 0; j < PPT; ++j) {
        int i = j * 512 + t;
        int slot = atomicAdd(&run[key[j]], 1);
        perm[b * M + slot] = i;
        xz_s[b * M + slot] = val[j];
    }
}

// z [B,C,M] -> zt [B,M,C], LDS-tiled transpose (conflict-free with +1 pad).
__global__ __launch_bounds__(256) void transpose_kernel(
    const float* __restrict__ z, float* __restrict__ zt)
{
    __shared__ float tile[C][65];
    const int b  = blockIdx.y;
    const int m0 = blockIdx.x * 64;
    const int tx = threadIdx.x & 63;
    const int ty = threadIdx.x >> 6;  // 0..3
    for (int c = ty; c < C; c += 4)
        tile[c][tx] = z[((size_t)b * C + c) * M + m0 + tx];  // coalesced in m
    __syncthreads();
    for (int mm = ty; mm < 64; mm += 4)
        zt[((size_t)b * M + m0 + mm) * C + tx] = tile[tx][mm];  // coalesced in c
}

// One wave per query. lane = channel. Scan candidate slots in bucket window.
__global__ __launch_bounds__(256) void gather_kernel(
    const float* __restrict__ x,
    const float* __restrict__ log_scale,
    const int* __restrict__ bucket_start,
    const int* __restrict__ perm,
    const float* __restrict__ xz_s,
    const float* __restrict__ zt,     // [B][M][C]
    float* __restrict__ out)          // [B][N][C]
{
    const int lane = threadIdx.x & 63;
    const int q = blockIdx.x * 4 + (threadIdx.x >> 6);
    const int b = q >> 12;            // q / N  (N = 4096)
    const int n = q & (N - 1);

    const float ls = log_scale[0];
    const float coef = -0.5f * __expf(-2.0f * ls);  // = -0.5 / scale^2  (negative)
    const float R = sqrtf(46.0f / (-coef));         // exp(coef*R^2) = e^-46

    const float xq = x[b * N + n];
    const int k0 = bucket_of(xq - R);
    const int k1 = bucket_of(xq + R);
    int s        = bucket_start[b * (NB + 1) + k0];
    const int s1 = bucket_start[b * (NB + 1) + k1 + 1];

    const float* xzb = xz_s + b * M;
    const int*   pb  = perm + b * M;
    const float* ztb = zt + (size_t)b * M * C;

    float acc = 0.0f;
    for (; s < s1; ++s) {
        float d = xq - xzb[s];          // broadcast load
        float w = __expf(coef * d * d);
        int m = pb[s];                  // broadcast load
        acc += w * ztb[m * C + lane];   // 256B coalesced row
    }
    out[(size_t)q * C + lane] = acc;
}

// Fallback gather reading z directly in [B,C,M] layout (no transpose needed).
__global__ __launch_bounds__(256) void gather_kernel_direct(
    const float* __restrict__ x,
    const float* __restrict__ log_scale,
    const int* __restrict__ bucket_start,
    const int* __restrict__ perm,
    const float* __restrict__ xz_s,
    const float* __restrict__ z,      // [B][C][M]
    float* __restrict__ out)
{
    const int lane = threadIdx.x & 63;
    const int q = blockIdx.x * 4 + (threadIdx.x >> 6);
    const int b = q >> 12;
    const int n = q & (N - 1);

    const float ls = log_scale[0];
    const float coef = -0.5f * __expf(-2.0f * ls);
    const float R = sqrtf(46.0f / (-coef));

    const float xq = x[b * N + n];
    const int k0 = bucket_of(xq - R);
    const int k1 = bucket_of(xq + R);
    int s        = bucket_start[b * (NB + 1) + k0];
    const int s1 = bucket_start[b * (NB + 1) + k1 + 1];

    const float* xzb = xz_s + b * M;
    const int*   pb  = perm + b * M;
    const float* zb  = z + (size_t)b * C * M + (size_t)lane * M;

    float acc = 0.0f;
    for (; s < s1; ++s) {
        float d = xq - xzb[s];
        float w = __expf(coef * d * d);
        int m = pb[s];
        acc += w * zb[m];               // strided gather, relies on L2
    }
    out[(size_t)q * C + lane] = acc;
}

extern "C" void kernel_launch(void* const* d_in, const int* in_sizes, int n_in,
                              void* d_out, int out_size, void* d_ws, size_t ws_size,
                              hipStream_t stream) {
    const float* xz = (const float*)d_in[0];  // [B,M,1]
    const float* z  = (const float*)d_in[1];  // [B,C,M]
    const float* x  = (const float*)d_in[2];  // [B,N,1]
    const float* ls = (const float*)d_in[3];  // scalar
    float* out = (float*)d_out;               // [B,N,C]

    char* ws = (char*)d_ws;
    const size_t zt_bytes   = (size_t)B * M * C * sizeof(float);   // 8 MB
    const size_t xzs_bytes  = (size_t)B * M * sizeof(float);       // 128 KB
    const size_t perm_bytes = (size_t)B * M * sizeof(int);         // 128 KB
    const size_t bs_bytes   = (size_t)B * (NB + 1) * sizeof(int);  // ~8 KB
    const size_t need_full  = zt_bytes + xzs_bytes + perm_bytes + bs_bytes;

    if (ws_size >= need_full) {
        float* zt    = (float*)ws;
        float* xz_s  = (float*)(ws + zt_bytes);
        int*   perm  = (int*)(ws + zt_bytes + xzs_bytes);
        int*   bst   = (int*)(ws + zt_bytes + xzs_bytes + perm_bytes);

        bin_kernel<<<B, 512, 0, stream>>>(xz, bst, perm, xz_s);
        transpose_kernel<<<dim3(M / 64, B), 256, 0, stream>>>(z, zt);
        gather_kernel<<<(B * N) / 4, 256, 0, stream>>>(x, ls, bst, perm, xz_s, zt, out);
    } else {
        float* xz_s  = (float*)ws;
        int*   perm  = (int*)(ws + xzs_bytes);
        int*   bst   = (int*)(ws + xzs_bytes + perm_bytes);

        bin_kernel<<<B, 512, 0, stream>>>(xz, bst, perm, xz_s);
        gather_kernel_direct<<<(B * N) / 4, 256, 0, stream>>>(x, ls, bst, perm, xz_s, z, out);
    }
}

// Round 2
// 191.071 us; speedup vs baseline: 1.5709x; 1.5709x over previous
//
#include <hip/hip_runtime.h>
#include <math.h>

#define B 4
#define N 4096
#define M 8192
#define C 64
#define NB 1024
#define XMIN (-64.0f)
#define INV_BW 8.0f   // bucket width 0.125

__device__ __forceinline__ int bucket_of(float v) {
    int k = (int)floorf((v - XMIN) * INV_BW);
    return min(max(k, 0), NB - 1);
}

__global__ __launch_bounds__(256) void zero_kernel(int* __restrict__ p, int n) {
    int i = blockIdx.x * 256 + threadIdx.x;
    if (i < n) p[i] = 0;
}

// One thread per point: histogram + remember key.
__global__ __launch_bounds__(256) void hist_kernel(
    const float* __restrict__ xz, int* __restrict__ gcount, int* __restrict__ keys)
{
    int i = blockIdx.x * 256 + threadIdx.x;   // 0..B*M
    int b = i >> 13;                          // M = 8192
    int k = bucket_of(xz[i]);
    keys[i] = k;
    atomicAdd(&gcount[b * NB + k], 1);
}

// One block per batch: exclusive scan of bucket counts.
__global__ __launch_bounds__(NB) void scan_kernel(
    const int* __restrict__ gcount, int* __restrict__ bucket_start, int* __restrict__ run)
{
    __shared__ int sc[NB];
    const int b = blockIdx.x, t = threadIdx.x;
    int cnt = gcount[b * NB + t];
    sc[t] = cnt;
    __syncthreads();
    for (int off = 1; off < NB; off <<= 1) {
        int add = (t >= off) ? sc[t - off] : 0;
        __syncthreads();
        sc[t] += add;
        __syncthreads();
    }
    int start = sc[t] - cnt;
    bucket_start[b * (NB + 1) + t] = start;
    run[b * NB + t] = start;
    if (t == NB - 1) bucket_start[b * (NB + 1) + NB] = sc[t];  // == M
}

// One thread per point: scatter {coord, index} into bucket-sorted order.
__global__ __launch_bounds__(256) void scatter_kernel(
    const float* __restrict__ xz, const int* __restrict__ keys,
    int* __restrict__ run, float2* __restrict__ pts)
{
    int i = blockIdx.x * 256 + threadIdx.x;
    int b = i >> 13;
    int slot = atomicAdd(&run[b * NB + keys[i]], 1);
    float2 p;
    p.x = xz[i];
    p.y = __int_as_float(i & (M - 1));
    pts[b * M + slot] = p;
}

// z [B,C,M] -> zt [B,M,C], LDS-tiled transpose.
__global__ __launch_bounds__(256) void transpose_kernel(
    const float* __restrict__ z, float* __restrict__ zt)
{
    __shared__ float tile[C][65];
    const int b  = blockIdx.y;
    const int m0 = blockIdx.x * 64;
    const int tx = threadIdx.x & 63;
    const int ty = threadIdx.x >> 6;  // 0..3
    for (int c = ty; c < C; c += 4)
        tile[c][tx] = z[((size_t)b * C + c) * M + m0 + tx];
    __syncthreads();
    for (int mm = ty; mm < 64; mm += 4)
        zt[((size_t)b * M + m0 + mm) * C + tx] = tile[tx][mm];
}

// One block (4 waves) per query. lane = channel; waves stride slots by 4;
// manual unroll x4 groups loads for memory-level parallelism.
__global__ __launch_bounds__(256) void gather_kernel(
    const float* __restrict__ x,
    const float* __restrict__ log_scale,
    const int* __restrict__ bucket_start,
    const float2* __restrict__ pts,
    const float* __restrict__ zt,     // [B][M][C]
    float* __restrict__ out)          // [B][N][C]
{
    const int lane = threadIdx.x & 63;
    const int w    = threadIdx.x >> 6;   // wave id 0..3
    const int q = blockIdx.x;
    const int b = q >> 12;                // N = 4096
    const int n = q & (N - 1);

    const float ls = log_scale[0];
    const float coef = -0.5f * __expf(-2.0f * ls);   // negative
    const float R = sqrtf(46.0f / (-coef));          // cutoff: exp(-46) ~ 1e-20

    const float xq = x[b * N + n];
    const int k0 = bucket_of(xq - R);
    const int k1 = bucket_of(xq + R);
    int s        = bucket_start[b * (NB + 1) + k0] + w;
    const int s1 = bucket_start[b * (NB + 1) + k1 + 1];

    const float2* pb  = pts + b * M;
    const float*  ztb = zt + (size_t)b * M * C;

    float acc = 0.0f;
    // unrolled: each wave handles slots s, s+4, s+8, s+12 per iteration
    for (; s + 12 < s1; s += 16) {
        float2 p0 = pb[s];
        float2 p1 = pb[s + 4];
        float2 p2 = pb[s + 8];
        float2 p3 = pb[s + 12];
        int m0 = __float_as_int(p0.y);
        int m1 = __float_as_int(p1.y);
        int m2 = __float_as_int(p2.y);
        int m3 = __float_as_int(p3.y);
        float r0 = ztb[(size_t)m0 * C + lane];
        float r1 = ztb[(size_t)m1 * C + lane];
        float r2 = ztb[(size_t)m2 * C + lane];
        float r3 = ztb[(size_t)m3 * C + lane];
        float d0 = xq - p0.x, d1 = xq - p1.x, d2 = xq - p2.x, d3 = xq - p3.x;
        acc += __expf(coef * d0 * d0) * r0;
        acc += __expf(coef * d1 * d1) * r1;
        acc += __expf(coef * d2 * d2) * r2;
        acc += __expf(coef * d3 * d3) * r3;
    }
    for (; s < s1; s += 4) {
        float2 p = pb[s];
        int m = __float_as_int(p.y);
        float d = xq - p.x;
        acc += __expf(coef * d * d) * ztb[(size_t)m * C + lane];
    }

    __shared__ float red[4][64];
    red[w][lane] = acc;
    __syncthreads();
    if (w == 0) {
        out[(size_t)q * C + lane] =
            red[0][lane] + red[1][lane] + red[2][lane] + red[3][lane];
    }
}

extern "C" void kernel_launch(void* const* d_in, const int* in_sizes, int n_in,
                              void* d_out, int out_size, void* d_ws, size_t ws_size,
                              hipStream_t stream) {
    const float* xz = (const float*)d_in[0];  // [B,M,1]
    const float* z  = (const float*)d_in[1];  // [B,C,M]
    const float* x  = (const float*)d_in[2];  // [B,N,1]
    const float* ls = (const float*)d_in[3];  // scalar
    float* out = (float*)d_out;               // [B,N,C]

    char* ws = (char*)d_ws;
    size_t off = 0;
    auto alloc = [&](size_t bytes) { void* p = ws + off; off += (bytes + 15) & ~size_t(15); return p; };

    float*  zt     = (float*)alloc((size_t)B * M * C * sizeof(float));   // 8 MB
    float2* pts    = (float2*)alloc((size_t)B * M * sizeof(float2));     // 256 KB
    int*    keys   = (int*)alloc((size_t)B * M * sizeof(int));           // 128 KB
    int*    gcount = (int*)alloc((size_t)B * NB * sizeof(int));          // 16 KB
    int*    run    = (int*)alloc((size_t)B * NB * sizeof(int));          // 16 KB
    int*    bst    = (int*)alloc((size_t)B * (NB + 1) * sizeof(int));    // 16.4 KB

    zero_kernel<<<(B * NB + 255) / 256, 256, 0, stream>>>(gcount, B * NB);
    hist_kernel<<<(B * M) / 256, 256, 0, stream>>>(xz, gcount, keys);
    scan_kernel<<<B, NB, 0, stream>>>(gcount, bst, run);
    scatter_kernel<<<(B * M) / 256, 256, 0, stream>>>(xz, keys, run, pts);
    transpose_kernel<<<dim3(M / 64, B), 256, 0, stream>>>(z, zt);
    gather_kernel<<<B * N, 256, 0, stream>>>(x, ls, bst, pts, zt, out);
}

// Round 3
// 140.621 us; speedup vs baseline: 2.1345x; 1.3588x over previous
//
#include <hip/hip_runtime.h>
#include <math.h>

#define B 4
#define N 4096
#define M 8192
#define C 64
#define NB 1024
#define XMIN (-64.0f)
#define INV_BW 8.0f    // bucket width 0.125
#define CUT 15.0f      // keep weights down to exp(-15); truncation err ~1e-4
#define QG 32          // queries per group
#define PCHUNK 128     // window points staged per chunk

__device__ __forceinline__ int bucket_of(float v) {
    int k = (int)floorf((v - XMIN) * INV_BW);
    return min(max(k, 0), NB - 1);
}

// Blocks 0..B-1: counting-sort points AND queries for batch b (1024 threads).
// Blocks B..B+B*M/64-1: transpose z [B,C,M] -> zt [B,M,C], one 64x64 tile each.
// The two roles are independent -> run in one dispatch, transpose hides bin.
__global__ __launch_bounds__(1024) void prep_kernel(
    const float* __restrict__ xz, const float* __restrict__ z,
    const float* __restrict__ x,
    int* __restrict__ bucket_start,    // [B][NB+1]
    float2* __restrict__ pts,          // [B][M]  (coord, m-index bits)
    float2* __restrict__ qpts,         // [B][N]  (coord, n-index bits)
    float* __restrict__ zt)            // [B][M][C]
{
    const int t = threadIdx.x;
    if (blockIdx.x < B) {
        const int b = blockIdx.x;
        __shared__ int hist[NB];
        __shared__ int run[NB];

        // ---- points: histogram ----
        hist[t] = 0;
        __syncthreads();
        float pv[8]; int pk[8];
        #pragma unroll
        for (int j = 0; j < 8; ++j) {
            int i = j * 1024 + t;
            float v = xz[b * M + i];
            pv[j] = v; pk[j] = bucket_of(v);
            atomicAdd(&hist[pk[j]], 1);
        }
        __syncthreads();
        int cnt = hist[t];
        for (int off = 1; off < NB; off <<= 1) {   // inclusive scan
            int add = (t >= off) ? hist[t - off] : 0;
            __syncthreads();
            hist[t] += add;
            __syncthreads();
        }
        int start = hist[t] - cnt;
        bucket_start[b * (NB + 1) + t] = start;
        if (t == NB - 1) bucket_start[b * (NB + 1) + NB] = hist[t];
        run[t] = start;
        __syncthreads();
        #pragma unroll
        for (int j = 0; j < 8; ++j) {
            int slot = atomicAdd(&run[pk[j]], 1);
            pts[b * M + slot] = make_float2(pv[j], __int_as_float(j * 1024 + t));
        }
        __syncthreads();

        // ---- queries: histogram + scan + scatter (reuse LDS) ----
        hist[t] = 0;
        __syncthreads();
        float qv[4]; int qk[4];
        #pragma unroll
        for (int j = 0; j < 4; ++j) {
            int i = j * 1024 + t;
            float v = x[b * N + i];
            qv[j] = v; qk[j] = bucket_of(v);
            atomicAdd(&hist[qk[j]], 1);
        }
        __syncthreads();
        cnt = hist[t];
        for (int off = 1; off < NB; off <<= 1) {
            int add = (t >= off) ? hist[t - off] : 0;
            __syncthreads();
            hist[t] += add;
            __syncthreads();
        }
        run[t] = hist[t] - cnt;
        __syncthreads();
        #pragma unroll
        for (int j = 0; j < 4; ++j) {
            int slot = atomicAdd(&run[qk[j]], 1);
            qpts[b * N + slot] = make_float2(qv[j], __int_as_float(j * 1024 + t));
        }
    } else {
        // ---- transpose tile ----
        const int tb = blockIdx.x - B;
        const int b  = tb >> 7;            // M/64 = 128 tiles per batch
        const int m0 = (tb & 127) * 64;
        __shared__ float tile[64][65];
        const int m = t & 63;
        for (int c = t >> 6; c < 64; c += 16)
            tile[c][m] = z[((size_t)b * C + c) * M + m0 + m];   // coalesced in m
        __syncthreads();
        const int cc = t & 63;
        for (int mm = t >> 6; mm < 64; mm += 16)
            zt[((size_t)b * M + m0 + mm) * C + cc] = tile[cc][mm];  // coalesced in c
    }
}

// One block per group of QG=32 sorted queries; 4 waves, each owns 8 queries.
// Window points staged through LDS in chunks of PCHUNK; zt rows loaded ONCE
// per group (vs once per query before) -> 32x less row traffic.
__global__ __launch_bounds__(256) void gather_kernel(
    const float* __restrict__ log_scale,
    const int* __restrict__ bucket_start,
    const float2* __restrict__ pts,
    const float2* __restrict__ qpts,
    const float* __restrict__ zt,      // [B][M][C]
    float* __restrict__ out)           // [B][N][C]
{
    const int lane = threadIdx.x & 63;
    const int w    = threadIdx.x >> 6;       // wave 0..3
    const int g = blockIdx.x;                // 0..B*(N/QG)-1
    const int b = g >> 7;                    // N/QG = 128 groups per batch
    const int g0 = (g & 127) * QG;

    __shared__ __align__(16) float zr[PCHUNK][C];   // 32 KB
    __shared__ float pcoord[PCHUNK];
    __shared__ int   pidx[PCHUNK];
    __shared__ float qc[QG];
    __shared__ int   qi[QG];

    const float ls   = log_scale[0];
    const float coef = -0.5f * __expf(-2.0f * ls);   // negative
    const float R    = sqrtf(CUT / (-coef));

    if (threadIdx.x < QG) {
        float2 qp = qpts[b * N + g0 + threadIdx.x];
        qc[threadIdx.x] = qp.x;
        qi[threadIdx.x] = __float_as_int(qp.y);
    }
    __syncthreads();

    float xmin = qc[0], xmax = qc[0];
    #pragma unroll
    for (int j = 1; j < QG; ++j) {
        xmin = fminf(xmin, qc[j]);
        xmax = fmaxf(xmax, qc[j]);
    }
    const int k0 = bucket_of(xmin - R);
    const int k1 = bucket_of(xmax + R);
    const int s0 = bucket_start[b * (NB + 1) + k0];
    const int s1 = bucket_start[b * (NB + 1) + k1 + 1];

    float q[8], acc[8];
    #pragma unroll
    for (int j = 0; j < 8; ++j) { q[j] = qc[w * 8 + j]; acc[j] = 0.0f; }

    const float2* pb  = pts + b * M;
    const float*  ztb = zt + (size_t)b * M * C;

    for (int cs = s0; cs < s1; cs += PCHUNK) {
        const int cnt = min(PCHUNK, s1 - cs);
        __syncthreads();                       // LDS reuse vs previous compute
        if (threadIdx.x < cnt) {
            float2 p = pb[cs + threadIdx.x];
            pcoord[threadIdx.x] = p.x;
            pidx[threadIdx.x]   = __float_as_int(p.y);
        }
        __syncthreads();
        // stage zt rows: 16 threads per row (16B each), coalesced 256B rows
        {
            const int c4 = threadIdx.x & 15;
            for (int p = threadIdx.x >> 4; p < cnt; p += 16) {
                float4 v = ((const float4*)ztb)[pidx[p] * 16 + c4];
                ((float4*)&zr[p][0])[c4] = v;
            }
        }
        __syncthreads();
        #pragma unroll 2
        for (int p = 0; p < cnt; ++p) {
            float xp = pcoord[p];
            float zv = zr[p][lane];
            #pragma unroll
            for (int j = 0; j < 8; ++j) {
                float d = q[j] - xp;
                acc[j] += __expf(coef * d * d) * zv;
            }
        }
    }

    #pragma unroll
    for (int j = 0; j < 8; ++j) {
        int n = qi[w * 8 + j];
        out[((size_t)b * N + n) * C + lane] = acc[j];
    }
}

extern "C" void kernel_launch(void* const* d_in, const int* in_sizes, int n_in,
                              void* d_out, int out_size, void* d_ws, size_t ws_size,
                              hipStream_t stream) {
    const float* xz = (const float*)d_in[0];  // [B,M,1]
    const float* z  = (const float*)d_in[1];  // [B,C,M]
    const float* x  = (const float*)d_in[2];  // [B,N,1]
    const float* ls = (const float*)d_in[3];  // scalar
    float* out = (float*)d_out;               // [B,N,C]

    char* ws = (char*)d_ws;
    size_t off = 0;
    auto alloc = [&](size_t bytes) { void* p = ws + off; off += (bytes + 255) & ~size_t(255); return p; };

    float*  zt   = (float*)alloc((size_t)B * M * C * sizeof(float));   // 8 MB
    float2* pts  = (float2*)alloc((size_t)B * M * sizeof(float2));     // 256 KB
    float2* qpts = (float2*)alloc((size_t)B * N * sizeof(float2));     // 128 KB
    int*    bst  = (int*)alloc((size_t)B * (NB + 1) * sizeof(int));    // 16.4 KB

    prep_kernel<<<B + B * M / 64, 1024, 0, stream>>>(xz, z, x, bst, pts, qpts, zt);
    gather_kernel<<<B * (N / QG), 256, 0, stream>>>(ls, bst, pts, qpts, zt, out);
}

// Round 4
// 103.389 us; speedup vs baseline: 2.9031x; 1.3601x over previous
//
#include <hip/hip_runtime.h>
#include <math.h>

#define B 4
#define N 4096
#define M 8192
#define C 64
#define NB 1024
#define XMIN (-64.0f)
#define INV_BW 8.0f    // bucket width 0.125
#define CUT 15.0f      // truncation: exp(-15) tail, err ~1e-4 << 0.43 threshold
#define QG 16          // queries per group (sorted)
#define PCH 64         // points staged per chunk

__device__ __forceinline__ int bucket_of(float v) {
    int k = (int)floorf((v - XMIN) * INV_BW);
    return min(max(k, 0), NB - 1);
}

// Blocks 0..B-1: counting-sort points AND queries for batch b (1024 threads).
// Blocks B..: transpose z [B,C,M] -> zt [B,M,C], one 64x64 tile each.
__global__ __launch_bounds__(1024) void prep_kernel(
    const float* __restrict__ xz, const float* __restrict__ z,
    const float* __restrict__ x,
    int* __restrict__ bucket_start,    // [B][NB+1]
    float* __restrict__ xs,            // [B][M] sorted coords
    int* __restrict__ pidx,            // [B][M] sorted slot -> original m
    float* __restrict__ qcs,           // [B][N] sorted query coords
    int* __restrict__ qis,             // [B][N] sorted slot -> original n
    float* __restrict__ zt)            // [B][M][C]
{
    const int t = threadIdx.x;
    if (blockIdx.x < B) {
        const int b = blockIdx.x;
        __shared__ int hist[NB];
        __shared__ int run[NB];

        // ---- points ----
        hist[t] = 0;
        __syncthreads();
        float pv[8]; int pk[8];
        #pragma unroll
        for (int j = 0; j < 8; ++j) {
            int i = j * 1024 + t;
            float v = xz[b * M + i];
            pv[j] = v; pk[j] = bucket_of(v);
            atomicAdd(&hist[pk[j]], 1);
        }
        __syncthreads();
        int cnt = hist[t];
        for (int off = 1; off < NB; off <<= 1) {
            int add = (t >= off) ? hist[t - off] : 0;
            __syncthreads();
            hist[t] += add;
            __syncthreads();
        }
        int start = hist[t] - cnt;
        bucket_start[b * (NB + 1) + t] = start;
        if (t == NB - 1) bucket_start[b * (NB + 1) + NB] = hist[t];
        run[t] = start;
        __syncthreads();
        #pragma unroll
        for (int j = 0; j < 8; ++j) {
            int slot = atomicAdd(&run[pk[j]], 1);
            xs[b * M + slot]   = pv[j];
            pidx[b * M + slot] = j * 1024 + t;
        }
        __syncthreads();

        // ---- queries ----
        hist[t] = 0;
        __syncthreads();
        float qv[4]; int qk[4];
        #pragma unroll
        for (int j = 0; j < 4; ++j) {
            int i = j * 1024 + t;
            float v = x[b * N + i];
            qv[j] = v; qk[j] = bucket_of(v);
            atomicAdd(&hist[qk[j]], 1);
        }
        __syncthreads();
        cnt = hist[t];
        for (int off = 1; off < NB; off <<= 1) {
            int add = (t >= off) ? hist[t - off] : 0;
            __syncthreads();
            hist[t] += add;
            __syncthreads();
        }
        run[t] = hist[t] - cnt;
        __syncthreads();
        #pragma unroll
        for (int j = 0; j < 4; ++j) {
            int slot = atomicAdd(&run[qk[j]], 1);
            qcs[b * N + slot] = qv[j];
            qis[b * N + slot] = j * 1024 + t;
        }
    } else {
        const int tb = blockIdx.x - B;
        const int b  = tb >> 7;            // M/64 = 128 tiles per batch
        const int m0 = (tb & 127) * 64;
        __shared__ float tile[64][65];
        const int m = t & 63;
        for (int c = t >> 6; c < 64; c += 16)
            tile[c][m] = z[((size_t)b * C + c) * M + m0 + m];
        __syncthreads();
        const int cc = t & 63;
        for (int mm = t >> 6; mm < 64; mm += 16)
            zt[((size_t)b * M + m0 + mm) * C + cc] = tile[cc][mm];
    }
}

// One block per group of QG=16 sorted queries; 4 waves, each owns 4 queries.
// Weights computed lane-parallel (lanes=points) into wave-private LDS rows;
// zt rows staged direct-to-LDS via global_load_lds (16B/lane, gathered).
__global__ __launch_bounds__(256) void gather_kernel(
    const float* __restrict__ log_scale,
    const int* __restrict__ bucket_start,
    const float* __restrict__ xs,
    const int* __restrict__ pidx,
    const float* __restrict__ qcs,
    const int* __restrict__ qis,
    const float* __restrict__ zt,      // [B][M][C]
    float* __restrict__ out)           // [B][N][C]
{
    const int t    = threadIdx.x;
    const int lane = t & 63;
    const int w    = t >> 6;            // wave 0..3
    const int g  = blockIdx.x;
    const int b  = g >> 8;              // N/QG = 256 groups per batch
    const int g0 = (g & 255) * QG;

    __shared__ __align__(16) float zr[PCH][C];    // 16 KB staged z rows
    __shared__ __align__(16) float wl[QG][PCH];   // 4 KB weights [q][p]
    __shared__ int   pr[PCH];                     // staged pidx chunk
    __shared__ float pcs[PCH];                    // staged point coords
    __shared__ float qc[QG];
    __shared__ int   qi[QG];

    const float ls   = log_scale[0];
    const float coef = -0.5f * __expf(-2.0f * ls);   // negative
    const float R    = sqrtf(CUT / (-coef));

    if (t < QG) {
        qc[t] = qcs[b * N + g0 + t];
        qi[t] = qis[b * N + g0 + t];
    }
    __syncthreads();

    float xmin = qc[0], xmax = qc[0];
    #pragma unroll
    for (int j = 1; j < QG; ++j) {
        xmin = fminf(xmin, qc[j]);
        xmax = fmaxf(xmax, qc[j]);
    }
    const int s0 = bucket_start[b * (NB + 1) + bucket_of(xmin - R)];
    const int s1 = bucket_start[b * (NB + 1) + bucket_of(xmax + R) + 1];

    const float q0 = qc[w * 4 + 0], q1 = qc[w * 4 + 1];
    const float q2 = qc[w * 4 + 2], q3 = qc[w * 4 + 3];

    if (s0 >= s1) {   // empty window (block-uniform): write zeros
        out[((size_t)b * N + qi[w * 4 + 0]) * C + lane] = 0.0f;
        out[((size_t)b * N + qi[w * 4 + 1]) * C + lane] = 0.0f;
        out[((size_t)b * N + qi[w * 4 + 2]) * C + lane] = 0.0f;
        out[((size_t)b * N + qi[w * 4 + 3]) * C + lane] = 0.0f;
        return;
    }

    float a0 = 0.f, a1 = 0.f, a2 = 0.f, a3 = 0.f;

    const float*  xsb  = xs   + b * M;
    const int*    pib  = pidx + b * M;
    const float4* zt4  = (const float4*)(zt + (size_t)b * M * C);

    for (int cs = s0; cs < s1; cs += PCH) {
        const int cnt = min(PCH, s1 - cs);
        __syncthreads();                 // zr/pr free from previous chunk
        if (t < PCH) {
            int row = min(cs + t, s1 - 1);
            pr[t]  = pib[row];
            pcs[t] = xsb[row];
        }
        __syncthreads();                 // pr/pcs ready
        // stage zt rows -> zr via global_load_lds (lane-contiguous LDS dest)
        #pragma unroll
        for (int i = 0; i < 4; ++i) {
            const int r = i * 16 + w * 4 + (lane >> 4);   // local row 0..63
            const float4* gp = zt4 + (size_t)pr[r] * 16 + (lane & 15);
            float* lp = &zr[i * 16 + w * 4][0];            // wave-uniform base
            __builtin_amdgcn_global_load_lds(
                (const __attribute__((address_space(1))) void*)gp,
                (__attribute__((address_space(3))) void*)lp, 16, 0, 0);
        }
        // overlap: wave-local weights, lanes = points
        {
            const float pcr  = pcs[lane];
            const bool  valid = (cs + lane) < s1;
            float d0 = q0 - pcr, d1 = q1 - pcr, d2 = q2 - pcr, d3 = q3 - pcr;
            wl[w * 4 + 0][lane] = valid ? __expf(coef * d0 * d0) : 0.0f;
            wl[w * 4 + 1][lane] = valid ? __expf(coef * d1 * d1) : 0.0f;
            wl[w * 4 + 2][lane] = valid ? __expf(coef * d2 * d2) : 0.0f;
            wl[w * 4 + 3][lane] = valid ? __expf(coef * d3 * d3) : 0.0f;
        }
        __syncthreads();                 // zr staged (barrier drains vmcnt)
        // dot phase: pure fmac; wl reads are uniform-address b128 broadcasts
        for (int p = 0; p < cnt; p += 4) {
            float zv0 = zr[p + 0][lane];
            float zv1 = zr[p + 1][lane];
            float zv2 = zr[p + 2][lane];
            float zv3 = zr[p + 3][lane];
            const float4 wa = *(const float4*)&wl[w * 4 + 0][p];
            const float4 wb = *(const float4*)&wl[w * 4 + 1][p];
            const float4 wc = *(const float4*)&wl[w * 4 + 2][p];
            const float4 wd = *(const float4*)&wl[w * 4 + 3][p];
            a0 = fmaf(wa.x, zv0, a0); a0 = fmaf(wa.y, zv1, a0);
            a0 = fmaf(wa.z, zv2, a0); a0 = fmaf(wa.w, zv3, a0);
            a1 = fmaf(wb.x, zv0, a1); a1 = fmaf(wb.y, zv1, a1);
            a1 = fmaf(wb.z, zv2, a1); a1 = fmaf(wb.w, zv3, a1);
            a2 = fmaf(wc.x, zv0, a2); a2 = fmaf(wc.y, zv1, a2);
            a2 = fmaf(wc.z, zv2, a2); a2 = fmaf(wc.w, zv3, a2);
            a3 = fmaf(wd.x, zv0, a3); a3 = fmaf(wd.y, zv1, a3);
            a3 = fmaf(wd.z, zv2, a3); a3 = fmaf(wd.w, zv3, a3);
        }
    }

    out[((size_t)b * N + qi[w * 4 + 0]) * C + lane] = a0;
    out[((size_t)b * N + qi[w * 4 + 1]) * C + lane] = a1;
    out[((size_t)b * N + qi[w * 4 + 2]) * C + lane] = a2;
    out[((size_t)b * N + qi[w * 4 + 3]) * C + lane] = a3;
}

extern "C" void kernel_launch(void* const* d_in, const int* in_sizes, int n_in,
                              void* d_out, int out_size, void* d_ws, size_t ws_size,
                              hipStream_t stream) {
    const float* xz = (const float*)d_in[0];  // [B,M,1]
    const float* z  = (const float*)d_in[1];  // [B,C,M]
    const float* x  = (const float*)d_in[2];  // [B,N,1]
    const float* ls = (const float*)d_in[3];  // scalar
    float* out = (float*)d_out;               // [B,N,C]

    char* ws = (char*)d_ws;
    size_t off = 0;
    auto alloc = [&](size_t bytes) { void* p = ws + off; off += (bytes + 255) & ~size_t(255); return p; };

    float* zt   = (float*)alloc((size_t)B * M * C * sizeof(float));   // 8 MB
    float* xs   = (float*)alloc((size_t)B * M * sizeof(float));       // 128 KB
    int*   pidx = (int*)alloc((size_t)B * M * sizeof(int));           // 128 KB
    float* qcs  = (float*)alloc((size_t)B * N * sizeof(float));       // 64 KB
    int*   qis  = (int*)alloc((size_t)B * N * sizeof(int));           // 64 KB
    int*   bst  = (int*)alloc((size_t)B * (NB + 1) * sizeof(int));    // 16.4 KB

    prep_kernel<<<B + B * M / 64, 1024, 0, stream>>>(xz, z, x, bst, xs, pidx, qcs, qis, zt);
    gather_kernel<<<B * (N / QG), 256, 0, stream>>>(ls, bst, xs, pidx, qcs, qis, zt, out);
}